// Round 2
// baseline (255.334 us; speedup 1.0000x reference)
//
#include <hip/hip_runtime.h>
#include <hip/hip_cooperative_groups.h>

namespace cg = cooperative_groups;

// B=2048, N=8192, F=512, H=8, F_=64
// softmax_n(e1[b]+e2[n]) == softmax_n(e2[n])  => output independent of b (broadcast).
// Deferred normalization: g[h] = sum_n exp(e2[h,n]) G[n],  s[h] = sum_n exp(e2[h,n]),
// out[b,:] = relu((g[h]/s[h]) @ W[h])  -- ONE pass over G.
//
// Stages (cooperative, 512 blocks x 256 threads):
//  S0: w2[h][f] = sum_e W[h,f,e]*att[h,64+e]            (4096 outputs, 8/block)
//  S1: per-block partial g,s over 16 rows of G           (main pass, reg accumulators)
//  S2: tree-reduce 512 partials -> g[4096], s[8]
//  S3: vr[h*64+e] = relu( (sum_f g[h,f] W[h,f,e]) / s[h] )   (one block per output)
//  S4: broadcast vr to out[2048][512]

#define HF   8
#define FDIM 512
#define FE   64
#define NG   8192
#define NBLK 512
#define NTHR 256

struct Ptrs {
    const float* G; const float* W; const float* att;
    float* out; float* w2; float* part; float* s_part;
    float* g; float* s_tot; float* vr;
};

__device__ __forceinline__ void stage0(const Ptrs& p, int bid, int tid) {
    int o = bid * 8 + (tid >> 5);           // 0..4095
    int l32 = tid & 31;
    int h = o >> 9, f = o & 511;
    const float* wp = p.W + ((size_t)(h * FDIM + f)) * FE;
    const float* a2 = p.att + h * 2 * FE + FE;
    float v = wp[l32] * a2[l32] + wp[l32 + 32] * a2[l32 + 32];
#pragma unroll
    for (int off = 16; off > 0; off >>= 1) v += __shfl_xor(v, off, 64);
    if (l32 == 0) p.w2[o] = v;
}

__device__ __forceinline__ void stage1(const Ptrs& p, int bid, int tid,
                                       float* lds, float* s_lds) {
    int wave = tid >> 6, lane = tid & 63;

    // w2 fragments into registers: lane owns f = lane*8..lane*8+7 for all 8 heads
    float4 w2a[HF], w2b[HF];
#pragma unroll
    for (int h = 0; h < HF; ++h) {
        const float* wp = p.w2 + h * FDIM + lane * 8;
        w2a[h] = *reinterpret_cast<const float4*>(wp);
        w2b[h] = *reinterpret_cast<const float4*>(wp + 4);
    }
    float4 accA[HF], accB[HF];
#pragma unroll
    for (int h = 0; h < HF; ++h) {
        accA[h] = make_float4(0.f, 0.f, 0.f, 0.f);
        accB[h] = make_float4(0.f, 0.f, 0.f, 0.f);
    }
    float s_acc[HF] = {};

    int n0 = bid * 16 + wave * 4;
    for (int r = 0; r < 4; ++r) {
        const float* gp = p.G + (size_t)(n0 + r) * FDIM + lane * 8;
        float4 g0 = *reinterpret_cast<const float4*>(gp);
        float4 g1 = *reinterpret_cast<const float4*>(gp + 4);
        float e[HF];
#pragma unroll
        for (int h = 0; h < HF; ++h)
            e[h] = g0.x * w2a[h].x + g0.y * w2a[h].y + g0.z * w2a[h].z + g0.w * w2a[h].w
                 + g1.x * w2b[h].x + g1.y * w2b[h].y + g1.z * w2b[h].z + g1.w * w2b[h].w;
#pragma unroll
        for (int off = 32; off > 0; off >>= 1) {
#pragma unroll
            for (int h = 0; h < HF; ++h) e[h] += __shfl_xor(e[h], off, 64);
        }
#pragma unroll
        for (int h = 0; h < HF; ++h) {
            float w = __expf(e[h]);          // all lanes identical
            s_acc[h] += w;
            accA[h].x = fmaf(w, g0.x, accA[h].x);
            accA[h].y = fmaf(w, g0.y, accA[h].y);
            accA[h].z = fmaf(w, g0.z, accA[h].z);
            accA[h].w = fmaf(w, g0.w, accA[h].w);
            accB[h].x = fmaf(w, g1.x, accB[h].x);
            accB[h].y = fmaf(w, g1.y, accB[h].y);
            accB[h].z = fmaf(w, g1.z, accB[h].z);
            accB[h].w = fmaf(w, g1.w, accB[h].w);
        }
    }

    // combine 4 waves' accumulators in LDS (fixed order -> deterministic)
    for (int w = 0; w < 4; ++w) {
        if (wave == w) {
#pragma unroll
            for (int h = 0; h < HF; ++h) {
                float* dst = lds + h * FDIM + lane * 8;
                if (w == 0) {
                    *reinterpret_cast<float4*>(dst)     = accA[h];
                    *reinterpret_cast<float4*>(dst + 4) = accB[h];
                } else {
                    float4 t0 = *reinterpret_cast<float4*>(dst);
                    float4 t1 = *reinterpret_cast<float4*>(dst + 4);
                    t0.x += accA[h].x; t0.y += accA[h].y; t0.z += accA[h].z; t0.w += accA[h].w;
                    t1.x += accB[h].x; t1.y += accB[h].y; t1.z += accB[h].z; t1.w += accB[h].w;
                    *reinterpret_cast<float4*>(dst)     = t0;
                    *reinterpret_cast<float4*>(dst + 4) = t1;
                }
            }
            if (lane == 0) {
#pragma unroll
                for (int h = 0; h < HF; ++h) s_lds[w * HF + h] = s_acc[h];
            }
        }
        __syncthreads();
    }

    float* dst = p.part + (size_t)bid * (HF * FDIM);
    for (int i = tid; i < HF * FDIM; i += NTHR) dst[i] = lds[i];
    if (tid < HF)
        p.s_part[bid * HF + tid] =
            (s_lds[tid] + s_lds[HF + tid]) + (s_lds[2 * HF + tid] + s_lds[3 * HF + tid]);
}

__device__ __forceinline__ void stage2(const Ptrs& p, int bid, int tid) {
    int half = tid >> 5, l32 = tid & 31;
    int elem = bid * 8 + half;              // 0..4095
    float v = 0.f;
#pragma unroll
    for (int k = 0; k < 16; ++k)
        v += p.part[(size_t)(l32 + 32 * k) * (HF * FDIM) + elem];
#pragma unroll
    for (int off = 16; off > 0; off >>= 1) v += __shfl_xor(v, off, 64);
    if (l32 == 0) p.g[elem] = v;

    if (bid == 0) {                          // s reduction (8 values x 512 partials)
        float sv = 0.f;
#pragma unroll
        for (int k = 0; k < 16; ++k)
            sv += p.s_part[(l32 + 32 * k) * HF + half];
#pragma unroll
        for (int off = 16; off > 0; off >>= 1) sv += __shfl_xor(sv, off, 64);
        if (l32 == 0) p.s_tot[half] = sv;
    }
}

__device__ __forceinline__ void stage3(const Ptrs& p, int bid, int tid, float* s_lds) {
    int h = bid >> 6, e = bid & 63;          // one (h,e) output per block
    const float* gh = p.g + h * FDIM;
    const float* wh = p.W + (size_t)h * FDIM * FE + e;
    float v = gh[tid] * wh[(size_t)tid * FE]
            + gh[tid + 256] * wh[(size_t)(tid + 256) * FE];
    int lane = tid & 63, wave = tid >> 6;
#pragma unroll
    for (int off = 32; off > 0; off >>= 1) v += __shfl_xor(v, off, 64);
    if (lane == 0) s_lds[wave] = v;
    __syncthreads();
    if (tid == 0) {
        float t = (s_lds[0] + s_lds[1]) + (s_lds[2] + s_lds[3]);
        p.vr[bid] = fmaxf(t / p.s_tot[h], 0.f);
    }
}

__device__ __forceinline__ void stage4(const Ptrs& p, int bid, int tid) {
    const float4* v4 = reinterpret_cast<const float4*>(p.vr);
    float4* o4 = reinterpret_cast<float4*>(p.out);
#pragma unroll
    for (int r = 0; r < 2; ++r) {
        int idx = bid * NTHR + tid + r * (NBLK * NTHR);   // 0..262143
        o4[idx] = v4[idx & 127];
    }
}

__global__ __launch_bounds__(NTHR, 2) void fused_all(Ptrs p) {
    cg::grid_group grid = cg::this_grid();
    __shared__ float lds[HF * FDIM];
    __shared__ float s_lds[4 * HF];
    int bid = blockIdx.x, tid = threadIdx.x;
    stage0(p, bid, tid);
    grid.sync();
    stage1(p, bid, tid, lds, s_lds);
    grid.sync();
    stage2(p, bid, tid);
    grid.sync();
    stage3(p, bid, tid, s_lds);
    grid.sync();
    stage4(p, bid, tid);
}

// ---- fallback path (plain launches) in case cooperative launch is rejected ----
__global__ __launch_bounds__(NTHR, 2) void k_s0(Ptrs p) { stage0(p, blockIdx.x, threadIdx.x); }
__global__ __launch_bounds__(NTHR, 2) void k_s1(Ptrs p) {
    __shared__ float lds[HF * FDIM];
    __shared__ float s_lds[4 * HF];
    stage1(p, blockIdx.x, threadIdx.x, lds, s_lds);
}
__global__ __launch_bounds__(NTHR, 2) void k_s2(Ptrs p) { stage2(p, blockIdx.x, threadIdx.x); }
__global__ __launch_bounds__(NTHR, 2) void k_s3(Ptrs p) {
    __shared__ float s_lds[4 * HF];
    stage3(p, blockIdx.x, threadIdx.x, s_lds);
}
__global__ __launch_bounds__(NTHR, 2) void k_s4(Ptrs p) { stage4(p, blockIdx.x, threadIdx.x); }

extern "C" void kernel_launch(void* const* d_in, const int* in_sizes, int n_in,
                              void* d_out, int out_size, void* d_ws, size_t ws_size,
                              hipStream_t stream) {
    // inputs: 0=X (mathematically unused), 1=G, 2=W, 3=att
    Ptrs p;
    p.G   = (const float*)d_in[1];
    p.W   = (const float*)d_in[2];
    p.att = (const float*)d_in[3];
    p.out = (float*)d_out;

    float* ws = (float*)d_ws;
    p.w2     = ws;               // 4096
    p.s_part = ws + 4096;        // 4096
    p.g      = ws + 8192;        // 4096
    p.s_tot  = ws + 12288;       // 64 (pad)
    p.vr     = ws + 12352;       // 512 (16B-aligned)
    p.part   = ws + 12864;       // 512*4096 floats (8 MB)

    Ptrs pl = p;
    void* args[] = { &pl };
    hipError_t err = hipLaunchCooperativeKernel((void*)fused_all, dim3(NBLK), dim3(NTHR),
                                                args, 0, stream);
    if (err != hipSuccess) {
        k_s0<<<NBLK, NTHR, 0, stream>>>(p);
        k_s1<<<NBLK, NTHR, 0, stream>>>(p);
        k_s2<<<NBLK, NTHR, 0, stream>>>(p);
        k_s3<<<NBLK, NTHR, 0, stream>>>(p);
        k_s4<<<NBLK, NTHR, 0, stream>>>(p);
    }
}

// Round 3
// 59.420 us; speedup vs baseline: 4.2971x; 4.2971x over previous
//
#include <hip/hip_runtime.h>

// B=2048, N=8192, F=512, H=8, F_=64
// Identity: softmax_n(e1[b]+e2[n]) == softmax_n(e2[n])  => output independent of b.
// Deferred normalization (shift-invariant softmax, magnitudes ~N(0,0.5) so exp is safe):
//   w2[h]   = W[h] @ a2[h]                       (8x512)
//   e2[h,n] = G[n,:] . w2[h,:]
//   g[h]    = sum_n exp(e2[h,n]) * G[n,:]        (one pass over G)
//   s[h]    = sum_n exp(e2[h,n])
//   out[b,:]= relu( (g[h]/s[h]) @ W[h] )         broadcast over all b
//
// 4 plain kernels (no grid.sync — cooperative sync measured ~50us/sync on MI355X):
//   k_w2    16 blk : w2
//   k_main 256 blk : partial (g,s) per block over 32 rows of G
//   k_gred  64 blk : reduce 256 partials -> g[4096]
//   k_final 64 blk : redundant s-reduce + redundant vr compute + 4MB broadcast write

#define HF   8
#define FDIM 512
#define FE   64
#define NG   8192
#define BX   2048
#define MB   256   // k_main blocks
#define ROWS 32    // rows of G per k_main block

__global__ __launch_bounds__(256) void k_w2(const float* __restrict__ W,
                                            const float* __restrict__ att,
                                            float* __restrict__ w2) {
    int id = blockIdx.x * 256 + threadIdx.x;      // 0..4095
    int h = id >> 9, f = id & 511;
    const float* a2 = att + h * (2 * FE) + FE;
    const float* wp = W + ((size_t)(h * FDIM + f)) * FE;
    float s = 0.f;
#pragma unroll
    for (int e = 0; e < FE; e += 4) {
        float4 w4 = *reinterpret_cast<const float4*>(wp + e);
        s += w4.x * a2[e] + w4.y * a2[e + 1] + w4.z * a2[e + 2] + w4.w * a2[e + 3];
    }
    w2[id] = s;
}

__global__ __launch_bounds__(256) void k_main(const float* __restrict__ G,
                                              const float* __restrict__ w2g,
                                              float* __restrict__ part,
                                              float* __restrict__ s_part) {
    __shared__ float lds[HF * FDIM];      // 16 KiB
    __shared__ float s_lds[4 * HF];
    int bid = blockIdx.x, tid = threadIdx.x;
    int wave = tid >> 6, lane = tid & 63;

    // w2 fragments: lane owns f = lane*8..lane*8+7 for all heads
    float4 w2a[HF], w2b[HF];
#pragma unroll
    for (int h = 0; h < HF; ++h) {
        const float* wp = w2g + h * FDIM + lane * 8;
        w2a[h] = *reinterpret_cast<const float4*>(wp);
        w2b[h] = *reinterpret_cast<const float4*>(wp + 4);
    }
    float4 accA[HF], accB[HF];
#pragma unroll
    for (int h = 0; h < HF; ++h) {
        accA[h] = make_float4(0.f, 0.f, 0.f, 0.f);
        accB[h] = make_float4(0.f, 0.f, 0.f, 0.f);
    }
    float s_acc[HF] = {};

    int n0 = bid * ROWS + wave * (ROWS / 4);
    for (int r = 0; r < ROWS / 4; ++r) {
        const float* gp = G + (size_t)(n0 + r) * FDIM + lane * 8;
        float4 g0 = *reinterpret_cast<const float4*>(gp);
        float4 g1 = *reinterpret_cast<const float4*>(gp + 4);
        float e[HF];
#pragma unroll
        for (int h = 0; h < HF; ++h)
            e[h] = g0.x * w2a[h].x + g0.y * w2a[h].y + g0.z * w2a[h].z + g0.w * w2a[h].w
                 + g1.x * w2b[h].x + g1.y * w2b[h].y + g1.z * w2b[h].z + g1.w * w2b[h].w;
#pragma unroll
        for (int off = 32; off > 0; off >>= 1) {
#pragma unroll
            for (int h = 0; h < HF; ++h) e[h] += __shfl_xor(e[h], off, 64);
        }
#pragma unroll
        for (int h = 0; h < HF; ++h) {
            float w = __expf(e[h]);       // identical in all lanes
            s_acc[h] += w;
            accA[h].x = fmaf(w, g0.x, accA[h].x);
            accA[h].y = fmaf(w, g0.y, accA[h].y);
            accA[h].z = fmaf(w, g0.z, accA[h].z);
            accA[h].w = fmaf(w, g0.w, accA[h].w);
            accB[h].x = fmaf(w, g1.x, accB[h].x);
            accB[h].y = fmaf(w, g1.y, accB[h].y);
            accB[h].z = fmaf(w, g1.z, accB[h].z);
            accB[h].w = fmaf(w, g1.w, accB[h].w);
        }
    }

    // fixed-order 4-wave combine in LDS (deterministic)
    for (int w = 0; w < 4; ++w) {
        if (wave == w) {
#pragma unroll
            for (int h = 0; h < HF; ++h) {
                float* dst = lds + h * FDIM + lane * 8;
                if (w == 0) {
                    *reinterpret_cast<float4*>(dst)     = accA[h];
                    *reinterpret_cast<float4*>(dst + 4) = accB[h];
                } else {
                    float4 t0 = *reinterpret_cast<float4*>(dst);
                    float4 t1 = *reinterpret_cast<float4*>(dst + 4);
                    t0.x += accA[h].x; t0.y += accA[h].y; t0.z += accA[h].z; t0.w += accA[h].w;
                    t1.x += accB[h].x; t1.y += accB[h].y; t1.z += accB[h].z; t1.w += accB[h].w;
                    *reinterpret_cast<float4*>(dst)     = t0;
                    *reinterpret_cast<float4*>(dst + 4) = t1;
                }
            }
            if (lane == 0) {
#pragma unroll
                for (int h = 0; h < HF; ++h) s_lds[w * HF + h] = s_acc[h];
            }
        }
        __syncthreads();
    }

    float* dst = part + (size_t)bid * (HF * FDIM);
    for (int i = tid; i < HF * FDIM; i += 256) dst[i] = lds[i];
    if (tid < HF)
        s_part[bid * HF + tid] =
            (s_lds[tid] + s_lds[HF + tid]) + (s_lds[2 * HF + tid] + s_lds[3 * HF + tid]);
}

__global__ __launch_bounds__(256) void k_gred(const float* __restrict__ part,
                                              float* __restrict__ g) {
    int bid = blockIdx.x, tid = threadIdx.x;
    int lane = tid & 63, chunk = tid >> 6;        // 4 chunks of 64 b-partials
    int elem = bid * 64 + lane;                   // 0..4095
    float v = 0.f;
#pragma unroll 8
    for (int j = 0; j < MB / 4; ++j)
        v += part[(size_t)(chunk * (MB / 4) + j) * (HF * FDIM) + elem];
    __shared__ float l[4][64];
    l[chunk][lane] = v;
    __syncthreads();
    if (tid < 64) g[bid * 64 + tid] = (l[0][tid] + l[1][tid]) + (l[2][tid] + l[3][tid]);
}

__global__ __launch_bounds__(256) void k_final(const float* __restrict__ W,
                                               const float* __restrict__ g,
                                               const float* __restrict__ s_part,
                                               float* __restrict__ out) {
    __shared__ float g_lds[HF * FDIM];   // 16 KiB
    __shared__ float s_tmp[256];
    __shared__ float s_h[HF];
    __shared__ float vr[HF * FE];        // 512
    int bid = blockIdx.x, tid = threadIdx.x;

    // redundant s reduction (8 KB, L2-hot), fixed order
    {
        int h = tid & 7, c = tid >> 3;            // 32 chunks of 8 b's
        float sv = 0.f;
#pragma unroll
        for (int j = 0; j < 8; ++j) sv += s_part[(c * 8 + j) * HF + h];
        s_tmp[tid] = sv;
    }
    __syncthreads();
    if (tid < HF) {
        float t = 0.f;
#pragma unroll
        for (int c = 0; c < 32; ++c) t += s_tmp[c * 8 + tid];
        s_h[tid] = t;
    }
    for (int i = tid; i < HF * FDIM; i += 256) g_lds[i] = g[i];
    __syncthreads();

    // redundant vr: wave w -> heads 2w, 2w+1; lane = e. Coalesced W reads (256B/iter).
    int wave = tid >> 6, lane = tid & 63;
#pragma unroll
    for (int hh = 0; hh < 2; ++hh) {
        int h = wave * 2 + hh;
        const float* wp = W + (size_t)h * FDIM * FE + lane;
        const float* gh = g_lds + h * FDIM;
        float v0 = 0.f, v1 = 0.f, v2 = 0.f, v3 = 0.f;
#pragma unroll 4
        for (int f = 0; f < FDIM; f += 4) {
            v0 = fmaf(gh[f],     wp[(size_t)f * FE],       v0);
            v1 = fmaf(gh[f + 1], wp[(size_t)(f + 1) * FE], v1);
            v2 = fmaf(gh[f + 2], wp[(size_t)(f + 2) * FE], v2);
            v3 = fmaf(gh[f + 3], wp[(size_t)(f + 3) * FE], v3);
        }
        float v = (v0 + v1) + (v2 + v3);
        vr[h * FE + lane] = fmaxf(v / s_h[h], 0.f);
    }
    __syncthreads();

    // broadcast: this block writes rows bid*32 .. bid*32+31
    const float4* v4 = reinterpret_cast<const float4*>(vr);
    float4* o4 = reinterpret_cast<float4*>(out);
    for (int i = tid; i < 32 * 128; i += 256) {
        int row = i >> 7, c = i & 127;
        o4[(size_t)(bid * 32 + row) * 128 + c] = v4[c];
    }
}

extern "C" void kernel_launch(void* const* d_in, const int* in_sizes, int n_in,
                              void* d_out, int out_size, void* d_ws, size_t ws_size,
                              hipStream_t stream) {
    // inputs: 0=X (mathematically unused), 1=G, 2=W, 3=att
    const float* G   = (const float*)d_in[1];
    const float* W   = (const float*)d_in[2];
    const float* att = (const float*)d_in[3];
    float* out = (float*)d_out;

    float* ws     = (float*)d_ws;
    float* w2     = ws;                    // 4096
    float* s_part = ws + 4096;             // 2048
    float* g      = ws + 6144;             // 4096
    float* part   = ws + 10240;            // 256*4096 = 1,048,576 (4 MB)

    k_w2  <<<16,  256, 0, stream>>>(W, att, w2);
    k_main<<<MB,  256, 0, stream>>>(G, w2, part, s_part);
    k_gred<<<64,  256, 0, stream>>>(part, g);
    k_final<<<64, 256, 0, stream>>>(W, g, s_part, out);
}

// Round 4
// 38.873 us; speedup vs baseline: 6.5684x; 1.5285x over previous
//
#include <hip/hip_runtime.h>

// B=2048, N=8192, F=512, H=8, F_=64
// Identity: softmax_n(e1[b]+e2[n]) == softmax_n(e2[n])  => output independent of b.
// Deferred normalization (softmax shift-invariant; e2 ~ N(0,0.45), exp safe):
//   w2[h]   = W[h] @ a2[h]                          (8x512)
//   g[h]    = sum_n exp(G[n].w2[h]) * G[n,:]        (one pass over G)
//   s[h]    = sum_n exp(G[n].w2[h])
//   out[b,:]= relu( (g[h]/s[h]) @ W[h] )            broadcast over all b
//
// 4 plain kernels; vr = g@W is DISTRIBUTED (vr_part per f-slice), never
// recomputed per-block from full W (round-3's k_final read 512 MB of W!).
//   k_w2     32 blk : w2 (2 lanes per output)
//   k_main  256 blk : partial (g,s) per block over 32 rows of G
//   k_gredvr 64 blk : reduce g-slice (h, 64 f's) + vr_part[b][e] = g_slice @ W-slice
//   k_final 256 blk : reduce vr_part + s (tiny, L2) -> relu(vr/s), write 8 rows each

#define HF   8
#define FDIM 512
#define FE   64
#define NG   8192
#define BX   2048
#define MB   256   // k_main blocks
#define ROWS 32    // rows of G per k_main block

__global__ __launch_bounds__(256) void k_w2(const float* __restrict__ W,
                                            const float* __restrict__ att,
                                            float* __restrict__ w2) {
    int gid = blockIdx.x * 256 + threadIdx.x;     // 0..8191
    int o = gid >> 1, half = gid & 1;             // o: 0..4095
    int h = o >> 9, f = o & 511;
    const float* a2 = att + h * (2 * FE) + FE + half * 32;
    const float* wp = W + ((size_t)(h * FDIM + f)) * FE + half * 32;
    float s = 0.f;
#pragma unroll
    for (int e = 0; e < 32; e += 4) {
        float4 w4 = *reinterpret_cast<const float4*>(wp + e);
        s += w4.x * a2[e] + w4.y * a2[e + 1] + w4.z * a2[e + 2] + w4.w * a2[e + 3];
    }
    s += __shfl_xor(s, 1, 64);
    if (half == 0) w2[o] = s;
}

__global__ __launch_bounds__(256) void k_main(const float* __restrict__ G,
                                              const float* __restrict__ w2g,
                                              float* __restrict__ part,
                                              float* __restrict__ s_part) {
    __shared__ float lds[HF * FDIM];      // 16 KiB
    __shared__ float s_lds[4 * HF];
    int bid = blockIdx.x, tid = threadIdx.x;
    int wave = tid >> 6, lane = tid & 63;

    float4 w2a[HF], w2b[HF];
#pragma unroll
    for (int h = 0; h < HF; ++h) {
        const float* wp = w2g + h * FDIM + lane * 8;
        w2a[h] = *reinterpret_cast<const float4*>(wp);
        w2b[h] = *reinterpret_cast<const float4*>(wp + 4);
    }
    float4 accA[HF], accB[HF];
#pragma unroll
    for (int h = 0; h < HF; ++h) {
        accA[h] = make_float4(0.f, 0.f, 0.f, 0.f);
        accB[h] = make_float4(0.f, 0.f, 0.f, 0.f);
    }
    float s_acc[HF] = {};

    int n0 = bid * ROWS + wave * (ROWS / 4);
    for (int r = 0; r < ROWS / 4; ++r) {
        const float* gp = G + (size_t)(n0 + r) * FDIM + lane * 8;
        float4 g0 = *reinterpret_cast<const float4*>(gp);
        float4 g1 = *reinterpret_cast<const float4*>(gp + 4);
        float e[HF];
#pragma unroll
        for (int h = 0; h < HF; ++h)
            e[h] = g0.x * w2a[h].x + g0.y * w2a[h].y + g0.z * w2a[h].z + g0.w * w2a[h].w
                 + g1.x * w2b[h].x + g1.y * w2b[h].y + g1.z * w2b[h].z + g1.w * w2b[h].w;
#pragma unroll
        for (int off = 32; off > 0; off >>= 1) {
#pragma unroll
            for (int h = 0; h < HF; ++h) e[h] += __shfl_xor(e[h], off, 64);
        }
#pragma unroll
        for (int h = 0; h < HF; ++h) {
            float w = __expf(e[h]);       // identical in all lanes
            s_acc[h] += w;
            accA[h].x = fmaf(w, g0.x, accA[h].x);
            accA[h].y = fmaf(w, g0.y, accA[h].y);
            accA[h].z = fmaf(w, g0.z, accA[h].z);
            accA[h].w = fmaf(w, g0.w, accA[h].w);
            accB[h].x = fmaf(w, g1.x, accB[h].x);
            accB[h].y = fmaf(w, g1.y, accB[h].y);
            accB[h].z = fmaf(w, g1.z, accB[h].z);
            accB[h].w = fmaf(w, g1.w, accB[h].w);
        }
    }

    // fixed-order 4-wave combine in LDS (deterministic)
    for (int w = 0; w < 4; ++w) {
        if (wave == w) {
#pragma unroll
            for (int h = 0; h < HF; ++h) {
                float* dst = lds + h * FDIM + lane * 8;
                if (w == 0) {
                    *reinterpret_cast<float4*>(dst)     = accA[h];
                    *reinterpret_cast<float4*>(dst + 4) = accB[h];
                } else {
                    float4 t0 = *reinterpret_cast<float4*>(dst);
                    float4 t1 = *reinterpret_cast<float4*>(dst + 4);
                    t0.x += accA[h].x; t0.y += accA[h].y; t0.z += accA[h].z; t0.w += accA[h].w;
                    t1.x += accB[h].x; t1.y += accB[h].y; t1.z += accB[h].z; t1.w += accB[h].w;
                    *reinterpret_cast<float4*>(dst)     = t0;
                    *reinterpret_cast<float4*>(dst + 4) = t1;
                }
            }
            if (lane == 0) {
#pragma unroll
                for (int h = 0; h < HF; ++h) s_lds[w * HF + h] = s_acc[h];
            }
        }
        __syncthreads();
    }

    float* dst = part + (size_t)bid * (HF * FDIM);
    for (int i = tid; i < HF * FDIM; i += 256) dst[i] = lds[i];
    if (tid < HF)
        s_part[bid * HF + tid] =
            (s_lds[tid] + s_lds[HF + tid]) + (s_lds[2 * HF + tid] + s_lds[3 * HF + tid]);
}

__global__ __launch_bounds__(256) void k_gredvr(const float* __restrict__ part,
                                                const float* __restrict__ W,
                                                float* __restrict__ vr_part) {
    int bid = blockIdx.x;                 // 0..63: h = bid>>3, f-slice = (bid&7)*64
    int h = bid >> 3, f0 = (bid & 7) * 64;
    int tid = threadIdx.x, lane = tid & 63, wv = tid >> 6;

    // reduce g-slice: lane = f offset, wave = quarter of the 256 partials
    float v = 0.f;
    int elem = h * FDIM + f0 + lane;
#pragma unroll 8
    for (int j = 0; j < MB / 4; ++j)
        v += part[(size_t)(wv * (MB / 4) + j) * (HF * FDIM) + elem];
    __shared__ float gs[4][64];
    gs[wv][lane] = v;
    __syncthreads();
    __shared__ float g_slice[64];
    if (tid < 64)
        g_slice[tid] = (gs[0][tid] + gs[1][tid]) + (gs[2][tid] + gs[3][tid]);
    __syncthreads();

    // vr_part[bid][e] = sum_{f in slice} g_slice[f] * W[h, f0+f, e]
    // wave wv covers 16 f's; lane = e; coalesced 256B W rows
    float acc = 0.f;
    const float* wp = W + (size_t)h * FDIM * FE + (size_t)(f0 + wv * 16) * FE + lane;
#pragma unroll
    for (int f = 0; f < 16; ++f)
        acc = fmaf(g_slice[wv * 16 + f], wp[(size_t)f * FE], acc);
    __shared__ float vp[4][64];
    vp[wv][lane] = acc;
    __syncthreads();
    if (tid < 64)
        vr_part[bid * 64 + tid] = (vp[0][tid] + vp[1][tid]) + (vp[2][tid] + vp[3][tid]);
}

__global__ __launch_bounds__(256) void k_final(const float* __restrict__ vr_part,
                                               const float* __restrict__ s_part,
                                               float* __restrict__ out) {
    __shared__ float vr[HF * FE];         // 512
    __shared__ float s_tmp[64];
    __shared__ float s_h[HF];
    int bid = blockIdx.x, tid = threadIdx.x;

    // redundant s reduction (8 KB, L2-hot), fixed order
    if (tid < 64) {
        int h = tid & 7, c = tid >> 3;    // 8 chunks of 32 partials
        float sv = 0.f;
#pragma unroll
        for (int j = 0; j < 32; ++j) sv += s_part[(c * 32 + j) * HF + h];
        s_tmp[tid] = sv;
    }
    __syncthreads();
    if (tid < HF) {
        float t = 0.f;
#pragma unroll
        for (int c = 0; c < 8; ++c) t += s_tmp[c * 8 + tid];
        s_h[tid] = t;
    }
    __syncthreads();

    // reduce vr_part (16 KB, L2-hot): vr[h,e] = relu( (sum_k vr_part[h*8+k][e]) / s_h )
#pragma unroll
    for (int r = 0; r < 2; ++r) {
        int o = tid + r * 256;
        int h = o >> 6, e = o & 63;
        float v = 0.f;
#pragma unroll
        for (int k = 0; k < 8; ++k) v += vr_part[(h * 8 + k) * 64 + e];
        vr[o] = fmaxf(v / s_h[h], 0.f);
    }
    __syncthreads();

    // write rows bid*8 .. bid*8+7
    const float4* v4 = reinterpret_cast<const float4*>(vr);
    float4* o4 = reinterpret_cast<float4*>(out);
    for (int i = tid; i < 8 * 128; i += 256) {
        int row = i >> 7, c = i & 127;
        o4[(size_t)(bid * 8 + row) * 128 + c] = v4[c];
    }
}

extern "C" void kernel_launch(void* const* d_in, const int* in_sizes, int n_in,
                              void* d_out, int out_size, void* d_ws, size_t ws_size,
                              hipStream_t stream) {
    // inputs: 0=X (mathematically unused), 1=G, 2=W, 3=att
    const float* G   = (const float*)d_in[1];
    const float* W   = (const float*)d_in[2];
    const float* att = (const float*)d_in[3];
    float* out = (float*)d_out;

    float* ws      = (float*)d_ws;
    float* w2      = ws;                   // 4096
    float* s_part  = ws + 4096;            // 2048
    float* vr_part = ws + 6144;            // 4096
    float* part    = ws + 10240;           // 256*4096 = 1,048,576 (4 MB)

    k_w2    <<<32,  256, 0, stream>>>(W, att, w2);
    k_main  <<<MB,  256, 0, stream>>>(G, w2, part, s_part);
    k_gredvr<<<64,  256, 0, stream>>>(part, W, vr_part);
    k_final <<<256, 256, 0, stream>>>(vr_part, s_part, out);
}